// Round 7
// baseline (233.397 us; speedup 1.0000x reference)
//
#include <hip/hip_runtime.h>

// YOLOv3 decode. R11: balanced monotone streams — the discriminating
// experiment between Model A (per-CU delivery cap: ~8.5 GB/s strided,
// ~11+ GB/s monotone; R8's 11 GB/s/CU lost only to 160 idle CUs) and
// Model B (chip-global ~2.2 TB/s cap for this read family: R5/R7/R10b
// all pinned there; R8's per-CU 11 appeared only while <2.2 was
// demanded chip-wide). Structure = R8's register-resident monotone
// channel sweep, balance fixed as the single variable:
//   52: 2 WGs per (b,a) slice (hw-halves, 460 KB each, 5.4 KB dense
//       burst per channel, monotone walk) -> 192 WGs
//   26: 1 WG per slice (230 KB monotone)                 -> 96 WGs
//   13: 1 scalar WG per slice (57 KB)                    -> 96 WGs
// Heavies dispatched first: 192 CUs take 460 KB, 64 CUs absorb the 192
// light WGs (~430 KB) -> per-CU shares within ~7%. No LDS, no barriers,
// no shuffles; argmax lane-local, strict > = first-max (jnp.argmax).
// Box channels 0..4 read at stream start (registers), classes 5..84
// follow — every byte read exactly once, strictly increasing addresses.

typedef float vf4 __attribute__((ext_vector_type(4)));

template<int HW4, int W, int SLOTS, int TL>
__device__ __forceinline__ void decode_tile(
    const float* __restrict__ in, const float* __restrict__ anch,
    float scale, float inv_case, float th,
    int slice, int colbase, int row_base,
    float* __restrict__ boxes, float* __restrict__ mask)
{
    constexpr int HW = HW4 * 4;
    const int t = threadIdx.x;
    if (SLOTS == 1 && t >= TL) return;          // no barriers -> safe early exit
    const int b = slice / 3;
    const int a = slice - b * 3;

    const vf4* __restrict__ base =
        reinterpret_cast<const vf4*>(in) + (size_t)slice * 85 * HW4 + colbase;

    auto act = [&](int s) { return (s + 1) * 256 <= TL ? true : (s * 256 + t < TL); };

    // channels 0..4: box params -> registers (stream start, monotone)
    vf4 o0[SLOTS], o1[SLOTS], o2[SLOTS], o3[SLOTS], o4[SLOTS];
#pragma unroll
    for (int s = 0; s < SLOTS; ++s) if (act(s)) {
        const int c4 = s * 256 + t;
        o0[s] = base[(size_t)0 * HW4 + c4];
        o1[s] = base[(size_t)1 * HW4 + c4];
        o2[s] = base[(size_t)2 * HW4 + c4];
        o3[s] = base[(size_t)3 * HW4 + c4];
        o4[s] = base[(size_t)4 * HW4 + c4];
    }

    // channels 5..84: class argmax, strictly monotone walk
    vf4  best[SLOTS];
    int4 bidx[SLOTS];
#pragma unroll
    for (int s = 0; s < SLOTS; ++s) if (act(s)) {
        best[s] = base[(size_t)5 * HW4 + s * 256 + t];
        bidx[s] = make_int4(0, 0, 0, 0);
    }
#pragma unroll 8
    for (int j = 1; j < 80; ++j) {
#pragma unroll
        for (int s = 0; s < SLOTS; ++s) if (act(s)) {
            const vf4 v = base[(size_t)(5 + j) * HW4 + s * 256 + t];
            if (v.x > best[s].x) { best[s].x = v.x; bidx[s].x = j; }
            if (v.y > best[s].y) { best[s].y = v.y; bidx[s].y = j; }
            if (v.z > best[s].z) { best[s].z = v.z; bidx[s].z = j; }
            if (v.w > best[s].w) { best[s].w = v.w; bidx[s].w = j; }
        }
    }

    const float a0 = anch[2 * a + 0], a1 = anch[2 * a + 1];
#pragma unroll
    for (int s = 0; s < SLOTS; ++s) {
        if (!act(s)) continue;
        const int c4 = colbase + s * 256 + t;
        const float e0[4] = { o0[s].x, o0[s].y, o0[s].z, o0[s].w };
        const float e1[4] = { o1[s].x, o1[s].y, o1[s].z, o1[s].w };
        const float e2[4] = { o2[s].x, o2[s].y, o2[s].z, o2[s].w };
        const float e3[4] = { o3[s].x, o3[s].y, o3[s].z, o3[s].w };
        const float e4[4] = { o4[s].x, o4[s].y, o4[s].z, o4[s].w };
        const int   bi[4] = { bidx[s].x, bidx[s].y, bidx[s].z, bidx[s].w };
#pragma unroll
        for (int k = 0; k < 4; ++k) {
            const int hw = c4 * 4 + k;
            const int hh = hw / W;               // compile-time W -> magic mul
            const int ww = hw - hh * W;
            const float px = 1.f / (1.f + __expf(-e0[k]));
            const float cx = ((float)ww + e1[k]) * scale;
            const float cy = ((float)hh + e2[k]) * scale;
            const float bw = a0 * __expf(e3[k]) * inv_case;
            const float bh = a1 * __expf(e4[k]) * inv_case;
            const int row = row_base + (b * HW + hw) * 3 + a;
            float2* ob2 = reinterpret_cast<float2*>(boxes + (size_t)row * 6);
            ob2[0] = make_float2(px, cx);
            ob2[1] = make_float2(cy, bw);
            ob2[2] = make_float2(bh, (float)bi[k]);
            mask[row] = (e0[k] > th) ? 1.0f : 0.0f;
        }
    }
}

// scalar monotone path for 13x13 (HW=169 odd; 5% of bytes)
__device__ __forceinline__ void decode_s13(
    const float* __restrict__ in, const float* __restrict__ anch,
    float scale, float inv_case, float th,
    int slice, float* __restrict__ boxes, float* __restrict__ mask)
{
    constexpr int HW = 169, W = 13;
    const int t = threadIdx.x;
    if (t >= HW) return;
    const int b = slice / 3;
    const int a = slice - b * 3;
    const float* __restrict__ p = in + (size_t)slice * 85 * HW + t;

    const float o0 = p[(size_t)0 * HW];
    const float o1 = p[(size_t)1 * HW];
    const float o2 = p[(size_t)2 * HW];
    const float o3 = p[(size_t)3 * HW];
    const float o4 = p[(size_t)4 * HW];

    float best = p[(size_t)5 * HW];
    int   bi   = 0;
#pragma unroll 8
    for (int j = 1; j < 80; ++j) {
        const float v = p[(size_t)(5 + j) * HW];
        if (v > best) { best = v; bi = j; }
    }

    const int hh = t / W;
    const int ww = t - hh * W;
    const float px = 1.f / (1.f + __expf(-o0));
    const float cx = ((float)ww + o1) * scale;
    const float cy = ((float)hh + o2) * scale;
    const float bw = anch[2 * a + 0] * __expf(o3) * inv_case;
    const float bh = anch[2 * a + 1] * __expf(o4) * inv_case;
    const int row = (b * HW + t) * 3 + a;        // 13-block row_base = 0
    float2* ob2 = reinterpret_cast<float2*>(boxes + (size_t)row * 6);
    ob2[0] = make_float2(px, cx);
    ob2[1] = make_float2(cy, bw);
    ob2[2] = make_float2(bh, (float)bi);
    mask[row] = (o0 > th) ? 1.0f : 0.0f;
}

__global__ __launch_bounds__(256) void detector_kernel(
    const float* __restrict__ in13, const float* __restrict__ in26,
    const float* __restrict__ in52,
    const float* __restrict__ a13, const float* __restrict__ a26,
    const float* __restrict__ a52,
    const float* __restrict__ thp, const int* __restrict__ casep,
    float* __restrict__ boxes, float* __restrict__ mask, int B)
{
    const int gx = blockIdx.x;
    const float th       = thp[0];
    const float inv_case = 1.0f / (float)casep[0];
    const int nH = B * 6;                        // 96 slices x 2 halves (52-scale)
    const int nM = B * 3;                        // 96 slices (26-scale)

    if (gx < nH) {
        const int slice = gx >> 1;
        const int half  = gx & 1;
        decode_tile<676, 52, 2, 338>(in52, a52, 8.0f * inv_case, inv_case, th,
                                     slice, half * 338,
                                     B * (169 + 676) * 3, boxes, mask);
    } else if (gx < nH + nM) {
        decode_tile<169, 26, 1, 169>(in26, a26, 16.0f * inv_case, inv_case, th,
                                     gx - nH, 0, B * 169 * 3, boxes, mask);
    } else {
        decode_s13(in13, a13, 32.0f * inv_case, inv_case, th,
                   gx - nH - nM, boxes, mask);
    }
}

extern "C" void kernel_launch(void* const* d_in, const int* in_sizes, int n_in,
                              void* d_out, int out_size, void* d_ws, size_t ws_size,
                              hipStream_t stream) {
    const float* in13 = (const float*)d_in[0];
    const float* in26 = (const float*)d_in[1];
    const float* in52 = (const float*)d_in[2];
    const float* a13  = (const float*)d_in[3];
    const float* a26  = (const float*)d_in[4];
    const float* a52  = (const float*)d_in[5];
    const float* thp  = (const float*)d_in[6];
    const int*   casep = (const int*)d_in[7];

    const int B = in_sizes[0] / (255 * 169);

    const int nrows = B * (169 + 676 + 2704) * 3;
    float* boxes = (float*)d_out;
    float* mask  = (float*)d_out + (size_t)nrows * 6;

    dim3 grid(B * 12);   // B*6 heavy halves + B*3 mid + B*3 small
    detector_kernel<<<grid, 256, 0, stream>>>(
        in13, in26, in52, a13, a26, a52, thp, casep, boxes, mask, B);
}

// Round 8
// 181.095 us; speedup vs baseline: 1.2888x; 1.2888x over previous
//
#include <hip/hip_runtime.h>

// YOLOv3 decode. R12: two-phase split. Ledger (per-CU read delivery):
// strided/channel-hopping mechanisms ALL saturate ~8.5 GB/s/CU (R5 8.6,
// R6 7.8, R7 LDS-DMA 8.5, R10b 8.6) regardless of outstanding (R7 had
// 30-60 wave-loads in flight); dense front-to-back streams reach 11-19
// (R8-heavy 11 @4 waves, copy 12.3, RMSNorm 19). R11 (3.8) was a
// collapsed-MLP confound. Untested cell: dense-monotone x balanced x
// >=8 waves/CU. Register-resident argmax forbids it in one kernel ->
// split: Phase 1 = copy-shaped streamers over fully-CONTIGUOUS channel
// blocks (52: 4 chunks x 20 classes/slice = 384 WGs, partial argmax to
// ws; 26: flat class region, full decode with LDS residue-combine, 96
// WGs; 13: proven R5 quad path). Explicit depth-3/6 load rotation.
// Phase 2 = 384 tiny WGs: merge 4 partials (ascending chunk, idx
// tie-break), read box channels, scattered output writes.

typedef float vf4 __attribute__((ext_vector_type(4)));

#define UPD1(B,I,V,C) { if ((V) > (B)) { (B)=(V); (I)=(C); } }
#define UPD4(bb,ii,vv,cc) \
    UPD1(bb.x, ii.x, vv.x, cc) UPD1(bb.y, ii.y, vv.y, cc) \
    UPD1(bb.z, ii.z, vv.z, cc) UPD1(bb.w, ii.w, vv.w, cc)
#define MRG1(B,I,V,C) { if ((V) > (B) || ((V)==(B) && (C) < (I))) { (B)=(V); (I)=(C); } }
#define MRG4(bb,ii,vv,cc) \
    MRG1(bb.x, ii.x, vv.x, cc.x) MRG1(bb.y, ii.y, vv.y, cc.y) \
    MRG1(bb.z, ii.z, vv.z, cc.z) MRG1(bb.w, ii.w, vv.w, cc.w)

__device__ __forceinline__ void store_p(float2* pb, int col, vf4 b, int4 i) {
    vf4* p = reinterpret_cast<vf4*>(pb + (size_t)col * 4);
    vf4 lo = {b.x, (float)i.x, b.y, (float)i.y};
    vf4 hi = {b.z, (float)i.z, b.w, (float)i.w};
    p[0] = lo; p[1] = hi;
}

// ---- Phase 1: 52-scale chunk streamer (20 contiguous channels, 216 KB) ----
__device__ __forceinline__ void p1_chunk52(
    const float* __restrict__ in52, float2* __restrict__ partial, int u)
{
    const int slice = u >> 2;            // b*3 + a
    const int k     = u & 3;             // chunk: classes 20k..20k+19
    const int t     = threadIdx.x;
    const vf4* __restrict__ cp = reinterpret_cast<const vf4*>(
        in52 + (size_t)slice * 85 * 2704 + (size_t)(5 + 20 * k) * 2704);

    const bool a2 = (t < 164);           // slot2 covers cols 512..675
    const int base = 20 * k;

    vf4 b0 = cp[t], b1 = cp[256 + t];
    vf4 b2 = a2 ? cp[512 + t] : b0;
    int4 i0 = {base, base, base, base}, i1 = i0, i2 = i0;

    vf4 n0 = cp[676 + t], n1 = cp[676 + 256 + t];
    vf4 n2 = a2 ? cp[676 + 512 + t] : n0;

#pragma unroll 2
    for (int c = 1; c < 19; ++c) {
        const vf4* ch = cp + (size_t)(c + 1) * 676;   // next channel in flight
        vf4 m0 = ch[t], m1 = ch[256 + t];
        vf4 m2 = a2 ? ch[512 + t] : m0;
        const int cls = base + c;
        UPD4(b0, i0, n0, cls) UPD4(b1, i1, n1, cls) UPD4(b2, i2, n2, cls)
        n0 = m0; n1 = m1; n2 = m2;
    }
    UPD4(b0, i0, n0, base + 19) UPD4(b1, i1, n1, base + 19) UPD4(b2, i2, n2, base + 19)

    float2* pb = partial + (size_t)u * 2704;
    store_p(pb, t, b0, i0);
    store_p(pb, 256 + t, b1, i1);
    if (a2) store_p(pb, 512 + t, b2, i2);
}

// ---- Phase 1: 26-scale full slice (flat class region + LDS combine) ----
__device__ __forceinline__ void p1_full26(
    const float* __restrict__ in26, const float* __restrict__ anch,
    float scale, float inv_case, float th, int slice, int rb26,
    float* __restrict__ boxes, float* __restrict__ mask,
    vf4* __restrict__ lbest, int4* __restrict__ lbi)
{
    const int t = threadIdx.x;
    const int b = slice / 3, a = slice - b * 3;
    const vf4* __restrict__ sp = reinterpret_cast<const vf4*>(in26)
                               + (size_t)slice * 85 * 169;
    const vf4* __restrict__ cp = sp + 5 * 169;   // 80 ch x 169 vf4, contiguous

    // slot positions p = {t, 256+t, 512+t}; (k4, col) = (p/169, p%169)
    const bool a2 = (t < 164);
    const int p0 = t,        k40 = p0 / 169, c0 = p0 - k40 * 169;
    const int p1 = 256 + t,  k41 = p1 / 169, c1 = p1 - k41 * 169;
    const int p2 = 512 + t,  k42 = p2 / 169, c2 = p2 - k42 * 169;
    (void)c0; (void)c1; (void)c2;

    vf4 b0 = cp[p0], b1 = cp[p1];
    vf4 b2 = a2 ? cp[p2] : b0;
    int4 i0 = {k40, k40, k40, k40}, i1 = {k41, k41, k41, k41}, i2 = {k42, k42, k42, k42};

    vf4 n0 = cp[676 + p0], n1 = cp[676 + p1];
    vf4 n2 = a2 ? cp[676 + p2] : n0;

#pragma unroll 2
    for (int g = 1; g < 19; ++g) {
        const vf4* gp = cp + (size_t)(g + 1) * 676;
        vf4 m0 = gp[p0], m1 = gp[p1];
        vf4 m2 = a2 ? gp[p2] : m0;
        const int g4 = 4 * g;
        UPD4(b0, i0, n0, g4 + k40) UPD4(b1, i1, n1, g4 + k41) UPD4(b2, i2, n2, g4 + k42)
        n0 = m0; n1 = m1; n2 = m2;
    }
    UPD4(b0, i0, n0, 76 + k40) UPD4(b1, i1, n1, 76 + k41) UPD4(b2, i2, n2, 76 + k42)

    lbest[p0] = b0; lbi[p0] = i0;
    lbest[p1] = b1; lbi[p1] = i1;
    if (a2) { lbest[p2] = b2; lbi[p2] = i2; }
    __syncthreads();

    if (t < 169) {
        vf4 bb = lbest[t]; int4 ii = lbi[t];
#pragma unroll
        for (int k4 = 1; k4 < 4; ++k4) {
            vf4 vb = lbest[k4 * 169 + t]; int4 vi = lbi[k4 * 169 + t];
            MRG4(bb, ii, vb, vi)
        }
        vf4 o0 = sp[t], o1 = sp[169 + t], o2 = sp[2 * 169 + t];
        vf4 o3 = sp[3 * 169 + t], o4 = sp[4 * 169 + t];
        const float A0 = anch[2 * a + 0], A1 = anch[2 * a + 1];
        const float e0[4] = {o0.x, o0.y, o0.z, o0.w};
        const float e1[4] = {o1.x, o1.y, o1.z, o1.w};
        const float e2[4] = {o2.x, o2.y, o2.z, o2.w};
        const float e3[4] = {o3.x, o3.y, o3.z, o3.w};
        const float e4[4] = {o4.x, o4.y, o4.z, o4.w};
        const int   bi[4] = {ii.x, ii.y, ii.z, ii.w};
        const float bv[4] = {bb.x, bb.y, bb.z, bb.w};
        (void)bv;
#pragma unroll
        for (int e = 0; e < 4; ++e) {
            const int hw = t * 4 + e;
            const int hh = hw / 26;
            const int ww = hw - hh * 26;
            const float px = 1.f / (1.f + __expf(-e0[e]));
            const float cx = ((float)ww + e1[e]) * scale;
            const float cy = ((float)hh + e2[e]) * scale;
            const float bw = A0 * __expf(e3[e]) * inv_case;
            const float bh = A1 * __expf(e4[e]) * inv_case;
            const int row = rb26 + (b * 676 + hw) * 3 + a;
            float2* ob2 = reinterpret_cast<float2*>(boxes + (size_t)row * 6);
            ob2[0] = make_float2(px, cx);
            ob2[1] = make_float2(cy, bw);
            ob2[2] = make_float2(bh, (float)bi[e]);
            mask[row] = (e0[e] > th) ? 1.0f : 0.0f;
        }
    }
}

// ---- Phase 1: 13-scale, proven R5 quad-seg path ----
__device__ __forceinline__ void decode4_13(
    const float* __restrict__ in, const float* __restrict__ anch,
    float scale, float inv_case, float th,
    int a, int t, int B,
    float* __restrict__ boxes, float* __restrict__ mask)
{
    constexpr int HW = 169, W = 13;
    if (t >= B * HW * 4) return;
    const int rt  = t >> 2;
    const int seg = t & 3;
    const int b   = rt / HW;
    const int hw  = rt - b * HW;

    const float* p = in + ((size_t)b * 255 + (size_t)a * 85) * HW + hw;
    const float* pc = p + (size_t)(5 + seg * 20) * HW;
    float v[20];
#pragma unroll
    for (int j = 0; j < 20; ++j) v[j] = pc[(size_t)j * HW];

    float best = v[0];
    int   bi   = seg * 20;
#pragma unroll
    for (int j = 1; j < 20; ++j)
        if (v[j] > best) { best = v[j]; bi = seg * 20 + j; }

    float o0 = p[0 * (size_t)HW], o1 = p[1 * (size_t)HW], o2 = p[2 * (size_t)HW];
    float o3 = p[3 * (size_t)HW], o4 = p[4 * (size_t)HW];

#pragma unroll
    for (int m = 1; m <= 2; m <<= 1) {
        float ob = __shfl_xor(best, m);
        int   oi = __shfl_xor(bi,   m);
        if (ob > best || (ob == best && oi < bi)) { best = ob; bi = oi; }
    }

    if (seg == 0) {
        const int h = hw / W, w = hw - (hw / W) * W;
        const float px = 1.0f / (1.0f + __expf(-o0));
        const float cx = ((float)w + o1) * scale;
        const float cy = ((float)h + o2) * scale;
        const float bw = anch[2 * a + 0] * __expf(o3) * inv_case;
        const float bh = anch[2 * a + 1] * __expf(o4) * inv_case;
        const int row = rt * 3 + a;          // 13-block row_base = 0
        float2* ob2 = reinterpret_cast<float2*>(boxes + (size_t)row * 6);
        ob2[0] = make_float2(px, cx);
        ob2[1] = make_float2(cy, bw);
        ob2[2] = make_float2(bh, (float)bi);
        mask[row] = (o0 > th) ? 1.0f : 0.0f;
    }
}

__global__ __launch_bounds__(256) void phase1_kernel(
    const float* __restrict__ in13, const float* __restrict__ in26,
    const float* __restrict__ in52,
    const float* __restrict__ a13, const float* __restrict__ a26,
    const float* __restrict__ thp, const int* __restrict__ casep,
    float2* __restrict__ partial,
    float* __restrict__ boxes, float* __restrict__ mask,
    int B, int nb13)
{
    __shared__ vf4 lbest[676];
    __shared__ int4 lbi[676];
    const int gx = blockIdx.x;
    const int n52c = B * 12, n26 = B * 3;

    if (gx < n52c) { p1_chunk52(in52, partial, gx); return; }
    if (gx < n52c + n26) {
        const float inv_case = 1.0f / (float)casep[0];
        p1_full26(in26, a26, 16.0f * inv_case, inv_case, thp[0],
                  gx - n52c, B * 169 * 3, boxes, mask, lbest, lbi);
        return;
    }
    const int u = gx - n52c - n26;
    const int a = u / nb13;
    const int t = (u - a * nb13) * 256 + threadIdx.x;
    const float inv_case = 1.0f / (float)casep[0];
    decode4_13(in13, a13, 32.0f * inv_case, inv_case, thp[0], a, t, B, boxes, mask);
}

// ---- Phase 2: merge 52-scale partials + box decode + scattered writes ----
__global__ __launch_bounds__(256) void phase2_kernel(
    const float* __restrict__ in52, const float* __restrict__ a52,
    const float* __restrict__ thp, const int* __restrict__ casep,
    const float2* __restrict__ partial,
    float* __restrict__ boxes, float* __restrict__ mask, int B)
{
    const int t = threadIdx.x;
    if (t >= 169) return;
    const int u = blockIdx.x;            // slice*4 + quarter
    const int slice = u >> 2, q = u & 3;
    const int b = slice / 3, a = slice - b * 3;
    const int col = q * 169 + t;         // vf4-col in [0,676)
    const float th = thp[0];
    const float inv_case = 1.0f / (float)casep[0];
    const float scale = 8.0f * inv_case;

    const vf4* pp = reinterpret_cast<const vf4*>(partial + (size_t)slice * 4 * 2704);
    vf4 e0 = pp[(size_t)col * 2], e1 = pp[(size_t)col * 2 + 1];
    vf4 bb = {e0.x, e0.z, e1.x, e1.z};
    int4 ii = {(int)e0.y, (int)e0.w, (int)e1.y, (int)e1.w};
#pragma unroll
    for (int k = 1; k < 4; ++k) {
        vf4 f0 = pp[(size_t)k * 1352 + col * 2];
        vf4 f1 = pp[(size_t)k * 1352 + col * 2 + 1];
        vf4 vb = {f0.x, f0.z, f1.x, f1.z};
        int4 vi = {(int)f0.y, (int)f0.w, (int)f1.y, (int)f1.w};
        MRG4(bb, ii, vb, vi)
    }

    const vf4* sp = reinterpret_cast<const vf4*>(in52) + (size_t)slice * 85 * 676;
    vf4 o0 = sp[col], o1 = sp[676 + col], o2 = sp[2 * 676 + col];
    vf4 o3 = sp[3 * 676 + col], o4 = sp[4 * 676 + col];

    const float A0 = a52[2 * a + 0], A1 = a52[2 * a + 1];
    const int rb52 = B * (169 + 676) * 3;
    const float e0a[4] = {o0.x, o0.y, o0.z, o0.w};
    const float e1a[4] = {o1.x, o1.y, o1.z, o1.w};
    const float e2a[4] = {o2.x, o2.y, o2.z, o2.w};
    const float e3a[4] = {o3.x, o3.y, o3.z, o3.w};
    const float e4a[4] = {o4.x, o4.y, o4.z, o4.w};
    const int   bia[4] = {ii.x, ii.y, ii.z, ii.w};
#pragma unroll
    for (int e = 0; e < 4; ++e) {
        const int hw = col * 4 + e;
        const int hh = hw / 52;
        const int ww = hw - hh * 52;
        const float px = 1.f / (1.f + __expf(-e0a[e]));
        const float cx = ((float)ww + e1a[e]) * scale;
        const float cy = ((float)hh + e2a[e]) * scale;
        const float bw = A0 * __expf(e3a[e]) * inv_case;
        const float bh = A1 * __expf(e4a[e]) * inv_case;
        const int row = rb52 + (b * 2704 + hw) * 3 + a;
        float2* ob2 = reinterpret_cast<float2*>(boxes + (size_t)row * 6);
        ob2[0] = make_float2(px, cx);
        ob2[1] = make_float2(cy, bw);
        ob2[2] = make_float2(bh, (float)bia[e]);
        mask[row] = (e0a[e] > th) ? 1.0f : 0.0f;
    }
}

extern "C" void kernel_launch(void* const* d_in, const int* in_sizes, int n_in,
                              void* d_out, int out_size, void* d_ws, size_t ws_size,
                              hipStream_t stream) {
    const float* in13 = (const float*)d_in[0];
    const float* in26 = (const float*)d_in[1];
    const float* in52 = (const float*)d_in[2];
    const float* a13  = (const float*)d_in[3];
    const float* a26  = (const float*)d_in[4];
    const float* a52  = (const float*)d_in[5];
    const float* thp  = (const float*)d_in[6];
    const int*   casep = (const int*)d_in[7];

    const int B = in_sizes[0] / (255 * 169);
    const int nb13 = (B * 169 * 4 + 255) / 256;

    const int nrows = B * (169 + 676 + 2704) * 3;
    float* boxes = (float*)d_out;
    float* mask  = (float*)d_out + (size_t)nrows * 6;
    float2* partial = (float2*)d_ws;     // B*12*2704*8 B = 8.3 MB @ B=32

    dim3 g1(B * 12 + B * 3 + 3 * nb13);  // 384 chunk52 + 96 full26 + 255 q13
    phase1_kernel<<<g1, 256, 0, stream>>>(
        in13, in26, in52, a13, a26, thp, casep, partial, boxes, mask, B, nb13);

    dim3 g2(B * 12);                     // 96 slices x 4 quarters
    phase2_kernel<<<g2, 256, 0, stream>>>(
        in52, a52, thp, casep, partial, boxes, mask, B);
}